// Round 5
// baseline (376.582 us; speedup 1.0000x reference)
//
#include <hip/hip_runtime.h>

#define NN 50000
#define NE 800000
#define GB1 391         // (NN+127)/128 gemm blocks in fused kernel
#define HB1 3125        // NE/256 hist blocks
#define BN_EPS 1e-5f

typedef __attribute__((ext_vector_type(8))) short short8;
typedef __attribute__((ext_vector_type(16))) float f32x16;
typedef __attribute__((ext_vector_type(4))) float f32x4;

static __device__ __forceinline__ unsigned short f2bf(float f) {
    union { float f; unsigned u; } v; v.f = f;
    unsigned r = (v.u + 0x7FFF + ((v.u >> 16) & 1)) >> 16;
    return (unsigned short)r;
}
static __device__ __forceinline__ float bf2f(unsigned short s) {
    union { unsigned u; float f; } v; v.u = ((unsigned)s) << 16;
    return v.f;
}

// ---------------- fused: layer-1 GEMM (blocks [0,GB1)) + degree/rank hist ----------------
// GEMM: Y = bf16(X @ W1), unscaled (dinv applied in aggregation).
__global__ __launch_bounds__(256) void k_gemm1_deg(
    const float* __restrict__ X, const float* __restrict__ W,
    unsigned short* __restrict__ Y,
    const int* __restrict__ dst, int* __restrict__ deg, int* __restrict__ rank) {
    __shared__ unsigned short Wt[128 * 136];  // [n][k]
    int t = threadIdx.x;

    if (blockIdx.x >= GB1) {
        // histogram role: one edge per thread
        int e = (blockIdx.x - GB1) * 256 + t;
        if (e < NE) rank[e] = atomicAdd(&deg[dst[e]], 1);
        return;
    }

    // GEMM role
    for (int i = t; i < 16384; i += 256) {
        int k = i >> 7, n = i & 127;
        Wt[n * 136 + k] = f2bf(W[i]);
    }
    __syncthreads();

    int wv = t >> 6;
    int l = t & 63;
    int l31 = l & 31;
    int khalf = l >> 5;
    int rowb = blockIdx.x * 128 + wv * 32;
    int myrow = rowb + l31;
    int rowc = myrow < NN ? myrow : NN - 1;

    f32x16 acc[4];
#pragma unroll
    for (int nt = 0; nt < 4; ++nt)
#pragma unroll
        for (int r = 0; r < 16; ++r) acc[nt][r] = 0.f;

#pragma unroll
    for (int ks = 0; ks < 8; ++ks) {
        int kk = ks * 16;
        const float* ap = X + (size_t)rowc * 128 + kk + khalf * 8;
        float4 f0 = ((const float4*)ap)[0];
        float4 f1 = ((const float4*)ap)[1];
        short8 a;
        a[0] = (short)f2bf(f0.x); a[1] = (short)f2bf(f0.y);
        a[2] = (short)f2bf(f0.z); a[3] = (short)f2bf(f0.w);
        a[4] = (short)f2bf(f1.x); a[5] = (short)f2bf(f1.y);
        a[6] = (short)f2bf(f1.z); a[7] = (short)f2bf(f1.w);
#pragma unroll
        for (int nt = 0; nt < 4; ++nt) {
            short8 b = *(const short8*)&Wt[(nt * 32 + l31) * 136 + kk + khalf * 8];
            acc[nt] = __builtin_amdgcn_mfma_f32_32x32x16_bf16(a, b, acc[nt], 0, 0, 0);
        }
    }

#pragma unroll
    for (int r = 0; r < 16; ++r) {
        int m = (r & 3) + 8 * (r >> 2) + 4 * khalf;
        int grow = rowb + m;
        if (grow < NN) {
#pragma unroll
            for (int nt = 0; nt < 4; ++nt)
                Y[(size_t)grow * 128 + nt * 32 + l31] = f2bf(acc[nt][r]);
        }
    }
}

// ---------------- single-block scan: rowptr + dinv + BN fold ----------------
__global__ __launch_bounds__(1024) void k_scan_all(
    const int* __restrict__ deg, int* __restrict__ rowptr, float* __restrict__ dinv,
    const float* b1, const float* g1, const float* be1, const float* m1, const float* v1,
    const float* b2, const float* g2, const float* be2, const float* m2, const float* v2,
    float* sc1, float* sh1, float* sc2, float* sh2) {
    __shared__ int s[1024];
    int t = threadIdx.x;
    const int PER = 49;  // 1024*49 >= NN
    int base = t * PER;
    int sum = 0;
    for (int k = 0; k < PER; ++k) {
        int i = base + k;
        if (i < NN) sum += deg[i];
    }
    s[t] = sum;
    __syncthreads();
    for (int off = 1; off < 1024; off <<= 1) {
        int add = (t >= off) ? s[t - off] : 0;
        __syncthreads();
        s[t] += add;
        __syncthreads();
    }
    int run = s[t] - sum;  // exclusive prefix
    for (int k = 0; k < PER; ++k) {
        int i = base + k;
        if (i < NN) {
            int d = deg[i];
            rowptr[i] = run;
            dinv[i] = rsqrtf((float)(d + 1));
            run += d;
        }
    }
    if (t == 0) rowptr[NN] = NE;
    if (t < 128) {
        float s1 = rsqrtf(v1[t] + BN_EPS) * g1[t];
        sc1[t] = s1; sh1[t] = be1[t] + (b1[t] - m1[t]) * s1;
        float s2 = rsqrtf(v2[t] + BN_EPS) * g2[t];
        sc2[t] = s2; sh2[t] = be2[t] + (b2[t] - m2[t]) * s2;
    }
}

// ---------------- CSR fill: no atomics ----------------
__global__ void k_fill(const int* __restrict__ src, const int* __restrict__ dst,
                       const int* __restrict__ rowptr, const int* __restrict__ rank,
                       int* __restrict__ eidx) {
    int e = blockIdx.x * blockDim.x + threadIdx.x;
    if (e >= NE) return;
    eidx[rowptr[dst[e]] + rank[e]] = src[e];
}

// ---------------- MFMA GEMM 128->128 (unscaled) ----------------
__global__ __launch_bounds__(256) void k_mfma_gemm128(
    const unsigned short* __restrict__ Xb, const float* __restrict__ W,
    unsigned short* __restrict__ Y) {
    __shared__ unsigned short Wt[128 * 136];
    int t = threadIdx.x;
    for (int i = t; i < 16384; i += 256) {
        int k = i >> 7, n = i & 127;
        Wt[n * 136 + k] = f2bf(W[i]);
    }
    __syncthreads();

    int wv = t >> 6;
    int l = t & 63;
    int l31 = l & 31;
    int khalf = l >> 5;
    int rowb = blockIdx.x * 128 + wv * 32;
    int myrow = rowb + l31;
    int rowc = myrow < NN ? myrow : NN - 1;

    f32x16 acc[4];
#pragma unroll
    for (int nt = 0; nt < 4; ++nt)
#pragma unroll
        for (int r = 0; r < 16; ++r) acc[nt][r] = 0.f;

#pragma unroll
    for (int ks = 0; ks < 8; ++ks) {
        int kk = ks * 16;
        short8 a = *(const short8*)(Xb + (size_t)rowc * 128 + kk + khalf * 8);
#pragma unroll
        for (int nt = 0; nt < 4; ++nt) {
            short8 b = *(const short8*)&Wt[(nt * 32 + l31) * 136 + kk + khalf * 8];
            acc[nt] = __builtin_amdgcn_mfma_f32_32x32x16_bf16(a, b, acc[nt], 0, 0, 0);
        }
    }

#pragma unroll
    for (int r = 0; r < 16; ++r) {
        int m = (r & 3) + 8 * (r >> 2) + 4 * khalf;
        int grow = rowb + m;
        if (grow < NN) {
#pragma unroll
            for (int nt = 0; nt < 4; ++nt)
                Y[(size_t)grow * 128 + nt * 32 + l31] = f2bf(acc[nt][r]);
        }
    }
}

// ---------------- MFMA GEMM 128->16 (unscaled) ----------------
__global__ __launch_bounds__(256) void k_mfma_gemm16(
    const unsigned short* __restrict__ Xb, const float* __restrict__ W3,
    unsigned short* __restrict__ Y) {
    __shared__ unsigned short Wt[16 * 136];
    int t = threadIdx.x;
    for (int i = t; i < 2048; i += 256) {
        int k = i >> 4, n = i & 15;
        Wt[n * 136 + k] = f2bf(W3[i]);
    }
    __syncthreads();

    int wv = t >> 6;
    int l = t & 63;
    int l15 = l & 15;
    int quad = l >> 4;
    int rowb = blockIdx.x * 256 + wv * 64;

    f32x4 acc[4];
#pragma unroll
    for (int mt = 0; mt < 4; ++mt)
#pragma unroll
        for (int r = 0; r < 4; ++r) acc[mt][r] = 0.f;

#pragma unroll
    for (int ks = 0; ks < 4; ++ks) {
        int kk = ks * 32;
        short8 b = *(const short8*)&Wt[l15 * 136 + kk + quad * 8];
#pragma unroll
        for (int mt = 0; mt < 4; ++mt) {
            int row = rowb + mt * 16 + l15;
            int rowc = row < NN ? row : NN - 1;
            short8 a = *(const short8*)(Xb + (size_t)rowc * 128 + kk + quad * 8);
            acc[mt] = __builtin_amdgcn_mfma_f32_16x16x32_bf16(a, b, acc[mt], 0, 0, 0);
        }
    }

#pragma unroll
    for (int mt = 0; mt < 4; ++mt) {
#pragma unroll
        for (int r = 0; r < 4; ++r) {
            int grow = rowb + mt * 16 + quad * 4 + r;
            if (grow < NN)
                Y[(size_t)grow * 16 + l15] = f2bf(acc[mt][r]);
        }
    }
}

// ---------------- aggregate 128ch: 1 node/wave, 8 edge-slots x 8 ch-lanes ----------------
// acc = dinv[node]*Ts[node] + sum dinv[s]*Ts[s]; out = relu(acc*dinv[node]*sc + sh)
__global__ __launch_bounds__(256) void k_agg128_bnrelu(
    const unsigned short* __restrict__ Ts, const int* __restrict__ rowptr,
    const int* __restrict__ eidx, const float* __restrict__ dinv,
    const float* __restrict__ sc, const float* __restrict__ sh,
    unsigned short* __restrict__ Z) {
    int node = blockIdx.x * 4 + (threadIdx.x >> 6);
    int l = threadIdx.x & 63;
    int grp = l >> 3;       // edge slot 0..7 (lane bits 3,4,5)
    int cl = l & 7;         // channel chunk: 16 ch = 2 float4
    const float4* Tv = (const float4*)Ts;
    float di = dinv[node];

    float acc[16];
    if (grp == 0) {
        float4 a0 = Tv[(size_t)node * 16 + cl * 2 + 0];
        float4 a1 = Tv[(size_t)node * 16 + cl * 2 + 1];
        const unsigned short* u0 = (const unsigned short*)&a0;
        const unsigned short* u1 = (const unsigned short*)&a1;
#pragma unroll
        for (int j = 0; j < 8; ++j) {
            acc[j] = di * bf2f(u0[j]);
            acc[8 + j] = di * bf2f(u1[j]);
        }
    } else {
#pragma unroll
        for (int j = 0; j < 16; ++j) acc[j] = 0.f;
    }

    int e0 = rowptr[node], e1 = rowptr[node + 1];
    for (int e = e0 + grp; e < e1; e += 8) {
        int s = eidx[e];
        float ds = dinv[s];
        float4 g0 = Tv[(size_t)s * 16 + cl * 2 + 0];
        float4 g1 = Tv[(size_t)s * 16 + cl * 2 + 1];
        const unsigned short* u0 = (const unsigned short*)&g0;
        const unsigned short* u1 = (const unsigned short*)&g1;
#pragma unroll
        for (int j = 0; j < 8; ++j) {
            acc[j] += ds * bf2f(u0[j]);
            acc[8 + j] += ds * bf2f(u1[j]);
        }
    }

    // reduce across the 8 edge slots (lane bits 3,4,5)
#pragma unroll
    for (int j = 0; j < 16; ++j) {
        acc[j] += __shfl_xor(acc[j], 8);
        acc[j] += __shfl_xor(acc[j], 16);
        acc[j] += __shfl_xor(acc[j], 32);
    }

    if (grp == 0) {
        float scl[16], shl[16];
#pragma unroll
        for (int q = 0; q < 4; ++q) {
            float4 scv = ((const float4*)sc)[cl * 4 + q];
            float4 shv = ((const float4*)sh)[cl * 4 + q];
            scl[q * 4 + 0] = scv.x; scl[q * 4 + 1] = scv.y;
            scl[q * 4 + 2] = scv.z; scl[q * 4 + 3] = scv.w;
            shl[q * 4 + 0] = shv.x; shl[q * 4 + 1] = shv.y;
            shl[q * 4 + 2] = shv.z; shl[q * 4 + 3] = shv.w;
        }
        float4 o0, o1;
        unsigned short* v0 = (unsigned short*)&o0;
        unsigned short* v1 = (unsigned short*)&o1;
#pragma unroll
        for (int j = 0; j < 8; ++j) {
            v0[j] = f2bf(fmaxf(acc[j] * di * scl[j] + shl[j], 0.f));
            v1[j] = f2bf(fmaxf(acc[8 + j] * di * scl[8 + j] + shl[8 + j], 0.f));
        }
        ((float4*)Z)[(size_t)node * 16 + cl * 2 + 0] = o0;
        ((float4*)Z)[(size_t)node * 16 + cl * 2 + 1] = o1;
    }
}

// ---------------- aggregate 16ch: 8 lanes/node, each lane = 1 edge slot w/ full row ----------------
__global__ __launch_bounds__(256) void k_agg16_lsm(
    const unsigned short* __restrict__ Tc, const int* __restrict__ rowptr,
    const int* __restrict__ eidx, const float* __restrict__ dinv,
    const float* __restrict__ b3, float* __restrict__ out) {
    int node = blockIdx.x * 32 + (threadIdx.x >> 3);
    if (node >= NN) return;
    int sub = threadIdx.x & 7;  // edge slot 0..7
    const float4* Tv = (const float4*)Tc;
    float di = dinv[node];

    float acc[16];
    if (sub == 0) {
        float4 a0 = Tv[(size_t)node * 2 + 0];
        float4 a1 = Tv[(size_t)node * 2 + 1];
        const unsigned short* u0 = (const unsigned short*)&a0;
        const unsigned short* u1 = (const unsigned short*)&a1;
#pragma unroll
        for (int j = 0; j < 8; ++j) {
            acc[j] = di * bf2f(u0[j]);
            acc[8 + j] = di * bf2f(u1[j]);
        }
    } else {
#pragma unroll
        for (int j = 0; j < 16; ++j) acc[j] = 0.f;
    }

    int e0 = rowptr[node], e1 = rowptr[node + 1];
    for (int e = e0 + sub; e < e1; e += 8) {
        int s = eidx[e];
        float ds = dinv[s];
        float4 g0 = Tv[(size_t)s * 2 + 0];
        float4 g1 = Tv[(size_t)s * 2 + 1];
        const unsigned short* u0 = (const unsigned short*)&g0;
        const unsigned short* u1 = (const unsigned short*)&g1;
#pragma unroll
        for (int j = 0; j < 8; ++j) {
            acc[j] += ds * bf2f(u0[j]);
            acc[8 + j] += ds * bf2f(u1[j]);
        }
    }

    // reduce across 8 slots (lane bits 0,1,2)
#pragma unroll
    for (int j = 0; j < 16; ++j) {
        acc[j] += __shfl_xor(acc[j], 1);
        acc[j] += __shfl_xor(acc[j], 2);
        acc[j] += __shfl_xor(acc[j], 4);
    }

    if (sub == 0) {
        float lg[16];
        float mx = -1e30f;
#pragma unroll
        for (int q = 0; q < 4; ++q) {
            float4 bv = ((const float4*)b3)[q];
            lg[q * 4 + 0] = acc[q * 4 + 0] * di + bv.x;
            lg[q * 4 + 1] = acc[q * 4 + 1] * di + bv.y;
            lg[q * 4 + 2] = acc[q * 4 + 2] * di + bv.z;
            lg[q * 4 + 3] = acc[q * 4 + 3] * di + bv.w;
        }
#pragma unroll
        for (int j = 0; j < 16; ++j) mx = fmaxf(mx, lg[j]);
        float se = 0.f;
#pragma unroll
        for (int j = 0; j < 16; ++j) se += expf(lg[j] - mx);
        float lse = mx + logf(se);
        float4* op = (float4*)(out + (size_t)node * 16);
        op[0] = make_float4(lg[0] - lse, lg[1] - lse, lg[2] - lse, lg[3] - lse);
        op[1] = make_float4(lg[4] - lse, lg[5] - lse, lg[6] - lse, lg[7] - lse);
        op[2] = make_float4(lg[8] - lse, lg[9] - lse, lg[10] - lse, lg[11] - lse);
        op[3] = make_float4(lg[12] - lse, lg[13] - lse, lg[14] - lse, lg[15] - lse);
    }
}

extern "C" void kernel_launch(void* const* d_in, const int* in_sizes, int n_in,
                              void* d_out, int out_size, void* d_ws, size_t ws_size,
                              hipStream_t stream) {
    const float* x  = (const float*)d_in[0];
    const int* ei   = (const int*)d_in[1];
    const float* W1 = (const float*)d_in[2];
    const float* b1 = (const float*)d_in[3];
    const float* g1 = (const float*)d_in[4];
    const float* be1 = (const float*)d_in[5];
    const float* m1 = (const float*)d_in[6];
    const float* v1 = (const float*)d_in[7];
    const float* W2 = (const float*)d_in[8];
    const float* b2 = (const float*)d_in[9];
    const float* g2 = (const float*)d_in[10];
    const float* be2 = (const float*)d_in[11];
    const float* m2 = (const float*)d_in[12];
    const float* v2 = (const float*)d_in[13];
    const float* W3 = (const float*)d_in[14];
    const float* b3 = (const float*)d_in[15];
    float* out = (float*)d_out;

    char* ws = (char*)d_ws;
    size_t off = 0;
    auto alloc = [&](size_t bytes) {
        char* p = ws + off;
        off = (off + bytes + 255) & ~255ULL;
        return p;
    };
    float* dinv  = (float*)alloc((size_t)NN * 4);
    int* degi    = (int*)alloc((size_t)NN * 4);
    int* rowptr  = (int*)alloc((size_t)(NN + 1) * 4);
    int* rank    = (int*)alloc((size_t)NE * 4);
    int* eidx    = (int*)alloc((size_t)NE * 4);
    float* sc1   = (float*)alloc(128 * 4);
    float* sh1   = (float*)alloc(128 * 4);
    float* sc2   = (float*)alloc(128 * 4);
    float* sh2   = (float*)alloc(128 * 4);
    unsigned short* TsA = (unsigned short*)alloc((size_t)NN * 128 * 2);
    unsigned short* actB = (unsigned short*)alloc((size_t)NN * 128 * 2);
    unsigned short* TcC = (unsigned short*)alloc((size_t)NN * 16 * 2);

    const int* srcp = ei;
    const int* dstp = ei + NE;

    hipMemsetAsync(degi, 0, (size_t)NN * 4, stream);

    // fused: layer-1 GEMM + degree/rank histogram (gemm blocks first for overlap)
    k_gemm1_deg<<<GB1 + HB1, 256, 0, stream>>>(x, W1, TsA, dstp, degi, rank);

    // rowptr + dinv + BN fold (single block)
    k_scan_all<<<1, 1024, 0, stream>>>(degi, rowptr, dinv,
                                       b1, g1, be1, m1, v1, b2, g2, be2, m2, v2,
                                       sc1, sh1, sc2, sh2);

    // CSR fill (no atomics)
    k_fill<<<HB1, 256, 0, stream>>>(srcp, dstp, rowptr, rank, eidx);

    // ---- layer 1 aggregate ----
    k_agg128_bnrelu<<<NN / 4, 256, 0, stream>>>(TsA, rowptr, eidx, dinv, sc1, sh1, actB);

    // ---- layer 2 ----
    k_mfma_gemm128<<<GB1, 256, 0, stream>>>(actB, W2, TsA);
    k_agg128_bnrelu<<<NN / 4, 256, 0, stream>>>(TsA, rowptr, eidx, dinv, sc2, sh2, actB);

    // ---- layer 3 ----
    k_mfma_gemm16<<<(NN + 255) / 256, 256, 0, stream>>>(actB, W3, TcC);
    k_agg16_lsm<<<(NN + 31) / 32, 256, 0, stream>>>(TcC, rowptr, eidx, dinv, b3, out);
}

// Round 6
// 263.480 us; speedup vs baseline: 1.4293x; 1.4293x over previous
//
#include <hip/hip_runtime.h>

#define NN 50000
#define NE 800000
#define NB 196          // (NN+255)/256
#define GB1 391         // (NN+127)/128 gemm blocks in fused kernel
#define HB1 3125        // NE/256 hist blocks
#define BN_EPS 1e-5f

typedef __attribute__((ext_vector_type(8))) short short8;
typedef __attribute__((ext_vector_type(16))) float f32x16;
typedef __attribute__((ext_vector_type(4))) float f32x4;

static __device__ __forceinline__ unsigned short f2bf(float f) {
    union { float f; unsigned u; } v; v.f = f;
    unsigned r = (v.u + 0x7FFF + ((v.u >> 16) & 1)) >> 16;
    return (unsigned short)r;
}
static __device__ __forceinline__ float bf2f(unsigned short s) {
    union { unsigned u; float f; } v; v.u = ((unsigned)s) << 16;
    return v.f;
}

// ---------------- fused: layer-1 GEMM (blocks [0,GB1)) + degree/rank hist ----------------
__global__ __launch_bounds__(256) void k_gemm1_deg(
    const float* __restrict__ X, const float* __restrict__ W,
    unsigned short* __restrict__ Y,
    const int* __restrict__ dst, int* __restrict__ deg, int* __restrict__ rank) {
    __shared__ unsigned short Wt[128 * 136];  // [n][k]
    int t = threadIdx.x;

    if (blockIdx.x >= GB1) {
        int e = (blockIdx.x - GB1) * 256 + t;
        if (e < NE) rank[e] = atomicAdd(&deg[dst[e]], 1);
        return;
    }

    for (int i = t; i < 16384; i += 256) {
        int k = i >> 7, n = i & 127;
        Wt[n * 136 + k] = f2bf(W[i]);
    }
    __syncthreads();

    int wv = t >> 6;
    int l = t & 63;
    int l31 = l & 31;
    int khalf = l >> 5;
    int rowb = blockIdx.x * 128 + wv * 32;
    int myrow = rowb + l31;
    int rowc = myrow < NN ? myrow : NN - 1;

    f32x16 acc[4];
#pragma unroll
    for (int nt = 0; nt < 4; ++nt)
#pragma unroll
        for (int r = 0; r < 16; ++r) acc[nt][r] = 0.f;

#pragma unroll
    for (int ks = 0; ks < 8; ++ks) {
        int kk = ks * 16;
        const float* ap = X + (size_t)rowc * 128 + kk + khalf * 8;
        float4 f0 = ((const float4*)ap)[0];
        float4 f1 = ((const float4*)ap)[1];
        short8 a;
        a[0] = (short)f2bf(f0.x); a[1] = (short)f2bf(f0.y);
        a[2] = (short)f2bf(f0.z); a[3] = (short)f2bf(f0.w);
        a[4] = (short)f2bf(f1.x); a[5] = (short)f2bf(f1.y);
        a[6] = (short)f2bf(f1.z); a[7] = (short)f2bf(f1.w);
#pragma unroll
        for (int nt = 0; nt < 4; ++nt) {
            short8 b = *(const short8*)&Wt[(nt * 32 + l31) * 136 + kk + khalf * 8];
            acc[nt] = __builtin_amdgcn_mfma_f32_32x32x16_bf16(a, b, acc[nt], 0, 0, 0);
        }
    }

#pragma unroll
    for (int r = 0; r < 16; ++r) {
        int m = (r & 3) + 8 * (r >> 2) + 4 * khalf;
        int grow = rowb + m;
        if (grow < NN) {
#pragma unroll
            for (int nt = 0; nt < 4; ++nt)
                Y[(size_t)grow * 128 + nt * 32 + l31] = f2bf(acc[nt][r]);
        }
    }
}

// ---------------- hierarchical scan (196 blocks), dinv fused ----------------
__global__ __launch_bounds__(256) void k_scan1(const int* __restrict__ deg,
                                               int* __restrict__ rowptr,
                                               int* __restrict__ bsum,
                                               float* __restrict__ dinv) {
    __shared__ int s[256];
    int t = threadIdx.x;
    int i = blockIdx.x * 256 + t;
    int v = (i < NN) ? deg[i] : 0;
    if (i < NN) dinv[i] = rsqrtf((float)(v + 1));  // +1 self-loop
    s[t] = v;
    __syncthreads();
    for (int off = 1; off < 256; off <<= 1) {
        int add = (t >= off) ? s[t - off] : 0;
        __syncthreads();
        s[t] += add;
        __syncthreads();
    }
    if (i < NN) rowptr[i] = s[t] - v;
    if (t == 255) bsum[blockIdx.x] = s[255];
}

// scan of block sums + BN fold (idle capacity reused)
__global__ __launch_bounds__(256) void k_scan2_bn(
    int* __restrict__ bsum,
    const float* b1, const float* g1, const float* be1, const float* m1, const float* v1,
    const float* b2, const float* g2, const float* be2, const float* m2, const float* v2,
    float* sc1, float* sh1, float* sc2, float* sh2) {
    __shared__ int s[256];
    int t = threadIdx.x;
    int v = (t < NB) ? bsum[t] : 0;
    s[t] = v;
    __syncthreads();
    for (int off = 1; off < 256; off <<= 1) {
        int add = (t >= off) ? s[t - off] : 0;
        __syncthreads();
        s[t] += add;
        __syncthreads();
    }
    if (t < NB) bsum[t] = s[t] - v;
    if (t < 128) {
        float s1 = rsqrtf(v1[t] + BN_EPS) * g1[t];
        sc1[t] = s1; sh1[t] = be1[t] + (b1[t] - m1[t]) * s1;
        float s2 = rsqrtf(v2[t] + BN_EPS) * g2[t];
        sc2[t] = s2; sh2[t] = be2[t] + (b2[t] - m2[t]) * s2;
    }
}

__global__ __launch_bounds__(256) void k_scan3(int* __restrict__ rowptr,
                                               const int* __restrict__ bsum) {
    int i = blockIdx.x * 256 + threadIdx.x;
    if (i < NN) rowptr[i] += bsum[blockIdx.x];
    if (i == 0) rowptr[NN] = NE;
}

// ---------------- CSR fill: no atomics ----------------
__global__ void k_fill(const int* __restrict__ src, const int* __restrict__ dst,
                       const int* __restrict__ rowptr, const int* __restrict__ rank,
                       int* __restrict__ eidx) {
    int e = blockIdx.x * blockDim.x + threadIdx.x;
    if (e >= NE) return;
    eidx[rowptr[dst[e]] + rank[e]] = src[e];
}

// ---------------- MFMA GEMM 128->128 (unscaled) ----------------
__global__ __launch_bounds__(256) void k_mfma_gemm128(
    const unsigned short* __restrict__ Xb, const float* __restrict__ W,
    unsigned short* __restrict__ Y) {
    __shared__ unsigned short Wt[128 * 136];
    int t = threadIdx.x;
    for (int i = t; i < 16384; i += 256) {
        int k = i >> 7, n = i & 127;
        Wt[n * 136 + k] = f2bf(W[i]);
    }
    __syncthreads();

    int wv = t >> 6;
    int l = t & 63;
    int l31 = l & 31;
    int khalf = l >> 5;
    int rowb = blockIdx.x * 128 + wv * 32;
    int myrow = rowb + l31;
    int rowc = myrow < NN ? myrow : NN - 1;

    f32x16 acc[4];
#pragma unroll
    for (int nt = 0; nt < 4; ++nt)
#pragma unroll
        for (int r = 0; r < 16; ++r) acc[nt][r] = 0.f;

#pragma unroll
    for (int ks = 0; ks < 8; ++ks) {
        int kk = ks * 16;
        short8 a = *(const short8*)(Xb + (size_t)rowc * 128 + kk + khalf * 8);
#pragma unroll
        for (int nt = 0; nt < 4; ++nt) {
            short8 b = *(const short8*)&Wt[(nt * 32 + l31) * 136 + kk + khalf * 8];
            acc[nt] = __builtin_amdgcn_mfma_f32_32x32x16_bf16(a, b, acc[nt], 0, 0, 0);
        }
    }

#pragma unroll
    for (int r = 0; r < 16; ++r) {
        int m = (r & 3) + 8 * (r >> 2) + 4 * khalf;
        int grow = rowb + m;
        if (grow < NN) {
#pragma unroll
            for (int nt = 0; nt < 4; ++nt)
                Y[(size_t)grow * 128 + nt * 32 + l31] = f2bf(acc[nt][r]);
        }
    }
}

// ---------------- MFMA GEMM 128->16 (unscaled) ----------------
__global__ __launch_bounds__(256) void k_mfma_gemm16(
    const unsigned short* __restrict__ Xb, const float* __restrict__ W3,
    unsigned short* __restrict__ Y) {
    __shared__ unsigned short Wt[16 * 136];
    int t = threadIdx.x;
    for (int i = t; i < 2048; i += 256) {
        int k = i >> 4, n = i & 15;
        Wt[n * 136 + k] = f2bf(W3[i]);
    }
    __syncthreads();

    int wv = t >> 6;
    int l = t & 63;
    int l15 = l & 15;
    int quad = l >> 4;
    int rowb = blockIdx.x * 256 + wv * 64;

    f32x4 acc[4];
#pragma unroll
    for (int mt = 0; mt < 4; ++mt)
#pragma unroll
        for (int r = 0; r < 4; ++r) acc[mt][r] = 0.f;

#pragma unroll
    for (int ks = 0; ks < 4; ++ks) {
        int kk = ks * 32;
        short8 b = *(const short8*)&Wt[l15 * 136 + kk + quad * 8];
#pragma unroll
        for (int mt = 0; mt < 4; ++mt) {
            int row = rowb + mt * 16 + l15;
            int rowc = row < NN ? row : NN - 1;
            short8 a = *(const short8*)(Xb + (size_t)rowc * 128 + kk + quad * 8);
            acc[mt] = __builtin_amdgcn_mfma_f32_16x16x32_bf16(a, b, acc[mt], 0, 0, 0);
        }
    }

#pragma unroll
    for (int mt = 0; mt < 4; ++mt) {
#pragma unroll
        for (int r = 0; r < 4; ++r) {
            int grow = rowb + mt * 16 + quad * 4 + r;
            if (grow < NN)
                Y[(size_t)grow * 16 + l15] = f2bf(acc[mt][r]);
        }
    }
}

// ---------------- aggregate 128ch: 1 node/wave, 8 edge-slots x 8 ch-lanes ----------------
__global__ __launch_bounds__(256) void k_agg128_bnrelu(
    const unsigned short* __restrict__ Ts, const int* __restrict__ rowptr,
    const int* __restrict__ eidx, const float* __restrict__ dinv,
    const float* __restrict__ sc, const float* __restrict__ sh,
    unsigned short* __restrict__ Z) {
    int node = blockIdx.x * 4 + (threadIdx.x >> 6);
    int l = threadIdx.x & 63;
    int grp = l >> 3;       // edge slot 0..7
    int cl = l & 7;         // channel chunk (16 ch)
    const float4* Tv = (const float4*)Ts;
    float di = dinv[node];

    float acc[16];
    if (grp == 0) {
        float4 a0 = Tv[(size_t)node * 16 + cl * 2 + 0];
        float4 a1 = Tv[(size_t)node * 16 + cl * 2 + 1];
        const unsigned short* u0 = (const unsigned short*)&a0;
        const unsigned short* u1 = (const unsigned short*)&a1;
#pragma unroll
        for (int j = 0; j < 8; ++j) {
            acc[j] = di * bf2f(u0[j]);
            acc[8 + j] = di * bf2f(u1[j]);
        }
    } else {
#pragma unroll
        for (int j = 0; j < 16; ++j) acc[j] = 0.f;
    }

    int e0 = rowptr[node], e1 = rowptr[node + 1];
    for (int e = e0 + grp; e < e1; e += 8) {
        int s = eidx[e];
        float ds = dinv[s];
        float4 g0 = Tv[(size_t)s * 16 + cl * 2 + 0];
        float4 g1 = Tv[(size_t)s * 16 + cl * 2 + 1];
        const unsigned short* u0 = (const unsigned short*)&g0;
        const unsigned short* u1 = (const unsigned short*)&g1;
#pragma unroll
        for (int j = 0; j < 8; ++j) {
            acc[j] += ds * bf2f(u0[j]);
            acc[8 + j] += ds * bf2f(u1[j]);
        }
    }

#pragma unroll
    for (int j = 0; j < 16; ++j) {
        acc[j] += __shfl_xor(acc[j], 8);
        acc[j] += __shfl_xor(acc[j], 16);
        acc[j] += __shfl_xor(acc[j], 32);
    }

    if (grp == 0) {
        float scl[16], shl[16];
#pragma unroll
        for (int q = 0; q < 4; ++q) {
            float4 scv = ((const float4*)sc)[cl * 4 + q];
            float4 shv = ((const float4*)sh)[cl * 4 + q];
            scl[q * 4 + 0] = scv.x; scl[q * 4 + 1] = scv.y;
            scl[q * 4 + 2] = scv.z; scl[q * 4 + 3] = scv.w;
            shl[q * 4 + 0] = shv.x; shl[q * 4 + 1] = shv.y;
            shl[q * 4 + 2] = shv.z; shl[q * 4 + 3] = shv.w;
        }
        float4 o0, o1;
        unsigned short* v0 = (unsigned short*)&o0;
        unsigned short* v1 = (unsigned short*)&o1;
#pragma unroll
        for (int j = 0; j < 8; ++j) {
            v0[j] = f2bf(fmaxf(acc[j] * di * scl[j] + shl[j], 0.f));
            v1[j] = f2bf(fmaxf(acc[8 + j] * di * scl[8 + j] + shl[8 + j], 0.f));
        }
        ((float4*)Z)[(size_t)node * 16 + cl * 2 + 0] = o0;
        ((float4*)Z)[(size_t)node * 16 + cl * 2 + 1] = o1;
    }
}

// ---------------- aggregate 16ch: 8 lanes/node + lsm ----------------
__global__ __launch_bounds__(256) void k_agg16_lsm(
    const unsigned short* __restrict__ Tc, const int* __restrict__ rowptr,
    const int* __restrict__ eidx, const float* __restrict__ dinv,
    const float* __restrict__ b3, float* __restrict__ out) {
    int node = blockIdx.x * 32 + (threadIdx.x >> 3);
    if (node >= NN) return;
    int sub = threadIdx.x & 7;
    const float4* Tv = (const float4*)Tc;
    float di = dinv[node];

    float acc[16];
    if (sub == 0) {
        float4 a0 = Tv[(size_t)node * 2 + 0];
        float4 a1 = Tv[(size_t)node * 2 + 1];
        const unsigned short* u0 = (const unsigned short*)&a0;
        const unsigned short* u1 = (const unsigned short*)&a1;
#pragma unroll
        for (int j = 0; j < 8; ++j) {
            acc[j] = di * bf2f(u0[j]);
            acc[8 + j] = di * bf2f(u1[j]);
        }
    } else {
#pragma unroll
        for (int j = 0; j < 16; ++j) acc[j] = 0.f;
    }

    int e0 = rowptr[node], e1 = rowptr[node + 1];
    for (int e = e0 + sub; e < e1; e += 8) {
        int s = eidx[e];
        float ds = dinv[s];
        float4 g0 = Tv[(size_t)s * 2 + 0];
        float4 g1 = Tv[(size_t)s * 2 + 1];
        const unsigned short* u0 = (const unsigned short*)&g0;
        const unsigned short* u1 = (const unsigned short*)&g1;
#pragma unroll
        for (int j = 0; j < 8; ++j) {
            acc[j] += ds * bf2f(u0[j]);
            acc[8 + j] += ds * bf2f(u1[j]);
        }
    }

#pragma unroll
    for (int j = 0; j < 16; ++j) {
        acc[j] += __shfl_xor(acc[j], 1);
        acc[j] += __shfl_xor(acc[j], 2);
        acc[j] += __shfl_xor(acc[j], 4);
    }

    if (sub == 0) {
        float lg[16];
        float mx = -1e30f;
#pragma unroll
        for (int q = 0; q < 4; ++q) {
            float4 bv = ((const float4*)b3)[q];
            lg[q * 4 + 0] = acc[q * 4 + 0] * di + bv.x;
            lg[q * 4 + 1] = acc[q * 4 + 1] * di + bv.y;
            lg[q * 4 + 2] = acc[q * 4 + 2] * di + bv.z;
            lg[q * 4 + 3] = acc[q * 4 + 3] * di + bv.w;
        }
#pragma unroll
        for (int j = 0; j < 16; ++j) mx = fmaxf(mx, lg[j]);
        float se = 0.f;
#pragma unroll
        for (int j = 0; j < 16; ++j) se += expf(lg[j] - mx);
        float lse = mx + logf(se);
        float4* op = (float4*)(out + (size_t)node * 16);
        op[0] = make_float4(lg[0] - lse, lg[1] - lse, lg[2] - lse, lg[3] - lse);
        op[1] = make_float4(lg[4] - lse, lg[5] - lse, lg[6] - lse, lg[7] - lse);
        op[2] = make_float4(lg[8] - lse, lg[9] - lse, lg[10] - lse, lg[11] - lse);
        op[3] = make_float4(lg[12] - lse, lg[13] - lse, lg[14] - lse, lg[15] - lse);
    }
}

extern "C" void kernel_launch(void* const* d_in, const int* in_sizes, int n_in,
                              void* d_out, int out_size, void* d_ws, size_t ws_size,
                              hipStream_t stream) {
    const float* x  = (const float*)d_in[0];
    const int* ei   = (const int*)d_in[1];
    const float* W1 = (const float*)d_in[2];
    const float* b1 = (const float*)d_in[3];
    const float* g1 = (const float*)d_in[4];
    const float* be1 = (const float*)d_in[5];
    const float* m1 = (const float*)d_in[6];
    const float* v1 = (const float*)d_in[7];
    const float* W2 = (const float*)d_in[8];
    const float* b2 = (const float*)d_in[9];
    const float* g2 = (const float*)d_in[10];
    const float* be2 = (const float*)d_in[11];
    const float* m2 = (const float*)d_in[12];
    const float* v2 = (const float*)d_in[13];
    const float* W3 = (const float*)d_in[14];
    const float* b3 = (const float*)d_in[15];
    float* out = (float*)d_out;

    char* ws = (char*)d_ws;
    size_t off = 0;
    auto alloc = [&](size_t bytes) {
        char* p = ws + off;
        off = (off + bytes + 255) & ~255ULL;
        return p;
    };
    float* dinv  = (float*)alloc((size_t)NN * 4);
    int* degi    = (int*)alloc((size_t)NN * 4);
    int* rowptr  = (int*)alloc((size_t)(NN + 1) * 4);
    int* bsum    = (int*)alloc(256 * 4);
    int* rank    = (int*)alloc((size_t)NE * 4);
    int* eidx    = (int*)alloc((size_t)NE * 4);
    float* sc1   = (float*)alloc(128 * 4);
    float* sh1   = (float*)alloc(128 * 4);
    float* sc2   = (float*)alloc(128 * 4);
    float* sh2   = (float*)alloc(128 * 4);
    unsigned short* TsA = (unsigned short*)alloc((size_t)NN * 128 * 2);
    unsigned short* actB = (unsigned short*)alloc((size_t)NN * 128 * 2);
    unsigned short* TcC = (unsigned short*)alloc((size_t)NN * 16 * 2);

    const int* srcp = ei;
    const int* dstp = ei + NE;

    hipMemsetAsync(degi, 0, (size_t)NN * 4, stream);

    // fused: layer-1 GEMM + degree/rank histogram
    k_gemm1_deg<<<GB1 + HB1, 256, 0, stream>>>(x, W1, TsA, dstp, degi, rank);

    // hierarchical scan + dinv + BN fold
    k_scan1<<<NB, 256, 0, stream>>>(degi, rowptr, bsum, dinv);
    k_scan2_bn<<<1, 256, 0, stream>>>(bsum, b1, g1, be1, m1, v1,
                                      b2, g2, be2, m2, v2, sc1, sh1, sc2, sh2);
    k_scan3<<<NB, 256, 0, stream>>>(rowptr, bsum);

    // CSR fill (no atomics)
    k_fill<<<HB1, 256, 0, stream>>>(srcp, dstp, rowptr, rank, eidx);

    // ---- layer 1 aggregate ----
    k_agg128_bnrelu<<<NN / 4, 256, 0, stream>>>(TsA, rowptr, eidx, dinv, sc1, sh1, actB);

    // ---- layer 2 ----
    k_mfma_gemm128<<<GB1, 256, 0, stream>>>(actB, W2, TsA);
    k_agg128_bnrelu<<<NN / 4, 256, 0, stream>>>(TsA, rowptr, eidx, dinv, sc2, sh2, actB);

    // ---- layer 3 ----
    k_mfma_gemm16<<<(NN + 255) / 256, 256, 0, stream>>>(actB, W3, TcC);
    k_agg16_lsm<<<(NN + 31) / 32, 256, 0, stream>>>(TcC, rowptr, eidx, dinv, b3, out);
}